// Round 6
// baseline (4635.157 us; speedup 1.0000x reference)
//
#include <hip/hip_runtime.h>

#define BB 32
#define QQ 16384
#define GG 128
#define KK 32
#define NN 9
#define TT 16       // GTs per K1 block
#define TH 1024     // K1 block size
#define HR 8        // elements per K1 thread (half-Q split)
#define NRANGE 2048 // ranges per (b, GT); range r covers {r + j*NRANGE, j<8}
#define RPL 32      // ranges per K2 lane (contiguous)
#define CAP 192     // compacted candidate key capacity
#define ACAP 96     // per-GT active-range capacity (expected ~40)
#define LCAP 12     // per-lane candidate slots; lc <= ceil(ACAP/8) = 12 always
#define UF 4        // K1 load prefetch batch

typedef unsigned long long u64;
typedef unsigned int u32;
typedef unsigned short u16;

#define INFF __uint_as_float(0x7F800000u)

// packed ascending key: (float bits of nonneg key) << 32 | idx
// lexicographic u64 compare == (value asc, index asc) == jax top_k tie rule
__device__ __forceinline__ u64 pack_asc(float key, u32 idx) {
  return (((u64)__float_as_uint(key)) << 32) | (u64)idx;
}

// EXACT reference squared distance: ((dx^2+dy^2)+dz^2)+dw^2, no contraction.
__device__ __forceinline__ float dist2_ref(const float4 g, const float4 p) {
#pragma clang fp contract(off)
  float dx = g.x - p.x;
  float dy = g.y - p.y;
  float dz = g.z - p.z;
  float dw = g.w - p.w;
  float s = dx * dx + dy * dy;
  s = s + dz * dz;
  s = s + dw * dw;
  return s;
}

// IoU exactly as reference (cxcywh -> xyxy, clip, same op order)
__device__ __forceinline__ float iou_ref(const float4 g, const float4 p) {
#pragma clang fp contract(off)
  float gx1 = g.x - 0.5f * g.z, gy1 = g.y - 0.5f * g.w;
  float gx2 = g.x + 0.5f * g.z, gy2 = g.y + 0.5f * g.w;
  float px1 = p.x - 0.5f * p.z, py1 = p.y - 0.5f * p.w;
  float px2 = p.x + 0.5f * p.z, py2 = p.y + 0.5f * p.w;
  float ltx = fmaxf(gx1, px1), lty = fmaxf(gy1, py1);
  float rbx = fminf(gx2, px2), rby = fminf(gy2, py2);
  float wx = fmaxf(rbx - ltx, 0.0f), wy = fmaxf(rby - lty, 0.0f);
  float inter = wx * wy;
  float aa = (gx2 - gx1) * (gy2 - gy1);
  float ab = (px2 - px1) * (py2 - py1);
  return inter / ((aa + ab) - inter);
}

// monotone bijection float -> u32 (total order preserved; no NaN inputs)
__device__ __forceinline__ u32 f2ord(float f) {
  u32 b = __float_as_uint(f);
  return (b & 0x80000000u) ? ~b : (b | 0x80000000u);
}
__device__ __forceinline__ float ord2f(u32 k) {
  return __uint_as_float((k & 0x80000000u) ? (k & 0x7FFFFFFFu) : ~k);
}

// round-UP-in-value f32 -> bf16 (monotone, result >= input):
// positives: +0xFFFF then truncate; negatives: truncation moves toward 0.
__device__ __forceinline__ u16 bf16up(float x) {
  u32 b = __float_as_uint(x);
  if (!(b >> 31)) b += 0xFFFFu;
  return (u16)(b >> 16);
}

// ================= K1: per-range min of s = |p|^2 - 2 g.p =================
// 512 blocks x 1024 thr; block = (batch b, GT-group m of 16, Q-half h).
// Thread t handles range r = h*1024 + t: elements {r + j*NRANGE, j<8}.
// No LDS, 2 blocks/CU, 8 waves/SIMD. Stores round-up bf16 (16 MB total).
__global__ __launch_bounds__(TH, 8) void atss_phase1(
    const float4* __restrict__ pred, const float4* __restrict__ gtb,
    u16* __restrict__ ws) {
  const int t = threadIdx.x;
  // XCD swizzle: f&7 = b>>2 -> same-batch blocks share an XCD.
  const int f = blockIdx.x;
  const int b = (f & 7) * 4 + (f >> 7);
  const int m = (f >> 3) & 7;
  const int h = (f >> 6) & 1;
  const int g0 = m * TT;

  float4 G[TT];
#pragma unroll
  for (int gg = 0; gg < TT; ++gg) G[gg] = gtb[b * GG + g0 + gg];

  const float4* pb = pred + (size_t)b * QQ;
  const int r = h * 1024 + t;  // this thread's range id

  float mn[TT];
#pragma unroll
  for (int gg = 0; gg < TT; ++gg) mn[gg] = INFF;

  float4 P[UF];
#pragma unroll
  for (int u = 0; u < UF; ++u) P[u] = pb[r + u * NRANGE];
#pragma unroll
  for (int j = 0; j < HR; j += UF) {
    float4 C[UF];
#pragma unroll
    for (int u = 0; u < UF; ++u) C[u] = P[u];
    if (j + UF < HR) {
#pragma unroll
      for (int u = 0; u < UF; ++u) P[u] = pb[r + (j + UF + u) * NRANGE];
    }
#pragma unroll
    for (int u = 0; u < UF; ++u) {
      float4 p = C[u];
      float pp = fmaf(p.x, p.x, fmaf(p.y, p.y, fmaf(p.z, p.z, p.w * p.w)));
      float qx = p.x + p.x, qy = p.y + p.y, qz = p.z + p.z, qw = p.w + p.w;
#pragma unroll
      for (int gg = 0; gg < TT; ++gg) {
        float acc = fmaf(-G[gg].x, qx, pp);
        acc = fmaf(-G[gg].y, qy, acc);
        acc = fmaf(-G[gg].z, qz, acc);
        acc = fmaf(-G[gg].w, qw, acc);
        mn[gg] = fminf(mn[gg], acc);
      }
    }
  }
  // ws layout: [(b*8 + m)*16 + gg][NRANGE] bf16, coalesced stores
  u16* seg = ws + (size_t)((b * 8 + m) * TT) * NRANGE;
#pragma unroll
  for (int gg = 0; gg < TT; ++gg) seg[gg * NRANGE + r] = bf16up(mn[gg]);
}

// ================= K2: per-GT selection, one 64-lane wave =================
// 4096 blocks x 64 thr. Design rule: NO dependent ballot/SALU chains --
// one shfl_up scan per compaction, broadcast-LDS rank select, 16-iter radix.
__global__ __launch_bounds__(64, 4) void atss_phase2(
    const float4* __restrict__ pred, const float4* __restrict__ gtb,
    const u16* __restrict__ ws, int* __restrict__ out) {
  __shared__ u64 kl[LCAP][64];  // per-lane strided candidate buffers (6 KB)
  __shared__ u64 kc[CAP];       // compacted (d,idx) keys
  __shared__ u16 sact[ACAP];    // active range ids
  __shared__ u32 ik[KK];        // iou rank keys
  __shared__ int kidx[KK];      // K-position -> pred idx (rank scatter)

  const int lane = threadIdx.x;
  // XCD swizzle consistent with K1: f&7 = b>>2.
  const int f = blockIdx.x;
  const int x = f & 7;
  const int jd = f >> 3;
  const int b = x * 4 + (jd & 3);
  const int g = jd >> 2;

  const float4 gt = gtb[b * GG + g];  // wave-uniform
  const float4* pb = pred + (size_t)b * QQ;
  const u16* vsrc =
      ws + (size_t)((b * 8 + (g >> 4)) * TT + (g & 15)) * NRANGE;

  // ---- load this GT's 2048 bf16 range-mins; lane owns 32 contiguous ----
  float V[RPL];
  {
    const uint4* v4 = (const uint4*)(vsrc + lane * RPL);
    uint4 qa = v4[0], qb = v4[1], qc = v4[2], qd = v4[3];
#define UNPK(W, base)                                   \
  V[(base)] = __uint_as_float((W) << 16);               \
  V[(base) + 1] = __uint_as_float((W) & 0xFFFF0000u);
    UNPK(qa.x, 0) UNPK(qa.y, 2) UNPK(qa.z, 4) UNPK(qa.w, 6)
    UNPK(qb.x, 8) UNPK(qb.y, 10) UNPK(qb.z, 12) UNPK(qb.w, 14)
    UNPK(qc.x, 16) UNPK(qc.y, 18) UNPK(qc.z, 20) UNPK(qc.w, 22)
    UNPK(qd.x, 24) UNPK(qd.y, 26) UNPK(qd.z, 28) UNPK(qd.w, 30)
#undef UNPK
  }

  // ---- per-lane 2 smallest of its 32 values (branchless) ----
  float m1 = INFF, m2 = INFF;
#pragma unroll
  for (int k = 0; k < RPL; ++k) {
    float v = V[k];
    float nm1 = fminf(m1, v);
    m2 = fminf(m2, fmaxf(m1, v));
    m1 = nm1;
  }

  // ---- U >= 32nd smallest of the 128 kept values, via 16-round radix ----
  // (top-16 ordered bits exact, low bits saturated -> U in [K32, K32*(1+2^-7)]).
  // Bound: >=32 DISTINCT ranges have bf16-min <= U -> true min <= U ->
  // >= 32 distinct elements have approx s <= U.
  u32 k1 = f2ord(m1), k2 = f2ord(m2);
  u32 pref = 0;
#pragma unroll
  for (int bit = 31; bit >= 16; --bit) {
    u32 tr = pref | (1u << bit);
    int c = __popcll(__ballot(k1 < tr)) + __popcll(__ballot(k2 < tr));
    if (c < 32) pref = tr;
  }
  float Us = ord2f(pref | 0xFFFFu);  // wave-uniform

  float gg2 = fmaf(gt.x, gt.x,
              fmaf(gt.y, gt.y, fmaf(gt.z, gt.z, gt.w * gt.w)));
  // Inflation: 0.025 rel covers bf16 round-up (2^-7) + radix quantization
  // (2^-7) + fma-vs-ref rounding (2e-5, proven R5-R8) with 1.5x headroom.
  const float sUs = Us + fabsf(Us) * 0.025f + 1e-5f;          // s-space
  const float T = fmaxf(Us + gg2, 0.0f) * 1.00005f + 1e-5f;   // d2-space

  // ---- compact active ranges: ONE prefix scan, zero ballots ----
  u32 amask = 0;
#pragma unroll
  for (int k = 0; k < RPL; ++k) amask |= (V[k] <= sUs) ? (1u << k) : 0u;
  int cnt = __popc(amask);
  int pre = cnt;
#pragma unroll
  for (int sj = 1; sj < 64; sj <<= 1) {
    int o = __shfl_up(pre, sj, 64);
    if (lane >= sj) pre += o;
  }
  const int na = __shfl(pre, 63, 64);  // wave-uniform total
  {
    int pos = pre - cnt;
    u32 mrem = amask;
    while (mrem) {
      int k = __ffs(mrem) - 1;
      mrem &= mrem - 1;
      if (pos < ACAP) sact[pos] = (u16)(lane * RPL + k);
      ++pos;
    }
  }

  // ---- exact-d2 collection into per-lane buffers (no cross-lane coord) --
  bool bad = (na > ACAP);
  int lc = 0;
  int n = 0;
  if (!bad) {
    // flat item space: item it = lane + 64*trip; entry it>>3 (8 lanes per
    // entry), element (it&7)*NRANGE. 2-deep pipeline hides sact+VMEM lat.
    const int total = na * HR;
    const int trips = (total + 63) >> 6;
    int it = lane;
    bool cv = it < total;
    int ci = 0;
    float4 cp;
    if (cv) {
      int e = sact[it >> 3];
      ci = (int)e + (it & 7) * NRANGE;
      cp = pb[ci];
    }
    for (int tr = 0; tr < trips; ++tr) {
      int itn = it + 64;
      bool nv = itn < total;
      int ni = 0;
      float4 np;
      if (nv) {
        int e = sact[itn >> 3];
        ni = (int)e + (itn & 7) * NRANGE;
        np = pb[ni];
      }
      if (cv) {
        float d2 = dist2_ref(gt, cp);
        if (d2 <= T) {
          // d = sqrtf(d2): IEEE, == jnp. lc < LCAP structurally guaranteed
          // (items/lane = trips <= ceil(ACAP*8/64) = LCAP); guard anyway.
          if (lc < LCAP) kl[lc][lane] = pack_asc(sqrtf(d2), (u32)ci);
          ++lc;
        }
      }
      it = itn;
      cv = nv;
      ci = ni;
      cp = np;
    }
    bad = __any(lc > LCAP);

    // ---- compact candidate count: second prefix scan ----
    int pre2 = lc;
#pragma unroll
    for (int sj = 1; sj < 64; sj <<= 1) {
      int o = __shfl_up(pre2, sj, 64);
      if (lane >= sj) pre2 += o;
    }
    n = __shfl(pre2, 63, 64);  // wave-uniform; >= 32 by the bound
    int excl = pre2 - lc;
    for (int i = 0; i < lc; ++i) {
      int dst = excl + i;
      if (dst < CAP) kc[dst] = kl[i][lane];
    }
    bad = bad || (n > 128);
  }

  // ---- pathological-only exact serial fallback ----
  if (bad) {
    if (lane == 0) {
      u64 best[KK];
      for (int l = 0; l < KK; ++l) best[l] = ~0ull;
      for (int i = 0; i < QQ; ++i) {
        float d = sqrtf(dist2_ref(gt, pb[i]));
        u64 pk = pack_asc(d, (u32)i);
        if (pk < best[KK - 1]) {
          int pos = KK - 1;
          while (pos > 0 && best[pos - 1] > pk) {
            best[pos] = best[pos - 1];
            --pos;
          }
          best[pos] = pk;
        }
      }
      for (int l = 0; l < KK; ++l) kidx[l] = (int)(best[l] & 0xFFFFFFFFull);
    }
  } else {
    // ---- top-32 rank select over n <= 128 keys: broadcast LDS reads ----
    // (independent ds_read_b64s, 4-unrolled; no dependent shuffle chain).
    // Ranks are unique (keys embed unique idx); exactly ranks 0..31 exist
    // among valid slots (n >= 32). Scatter idx to kidx[rank] -- no
    // ds_permute (its dest-lane addr wraps mod 64: ranks >= 64 would
    // corrupt lanes 0..31).
    u64 myA = (lane < n) ? kc[lane] : ~0ull;
    u64 myB = (lane + 64 < n) ? kc[lane + 64] : ~0ull;
    int rA = 0, rB = 0;
    const bool two = (n > 64);  // uniform branch
    if (!two) {
      int i = 0;
      for (; i + 4 <= n; i += 4) {
        u64 a0 = kc[i], a1 = kc[i + 1], a2 = kc[i + 2], a3 = kc[i + 3];
        rA += (int)(a0 < myA) + (int)(a1 < myA) + (int)(a2 < myA) +
              (int)(a3 < myA);
      }
      for (; i < n; ++i) rA += (int)(kc[i] < myA);
    } else {
      int i = 0;
      for (; i + 4 <= n; i += 4) {
        u64 a0 = kc[i], a1 = kc[i + 1], a2 = kc[i + 2], a3 = kc[i + 3];
        rA += (int)(a0 < myA) + (int)(a1 < myA) + (int)(a2 < myA) +
              (int)(a3 < myA);
        rB += (int)(a0 < myB) + (int)(a1 < myB) + (int)(a2 < myB) +
              (int)(a3 < myB);
      }
      for (; i < n; ++i) {
        u64 a0 = kc[i];
        rA += (int)(a0 < myA);
        rB += (int)(a0 < myB);
      }
    }
    if (lane < n && rA < KK) kidx[rA] = (int)(myA & 0xFFFFFFFFull);
    if (two && lane + 64 < n && rB < KK)
      kidx[rB] = (int)(myB & 0xFFFFFFFFull);
  }
  // same-wave DS ordering: kidx writes visible to this wave's reads
  const int pi = (lane < KK) ? kidx[lane] : 0;

  // ---- IoU of the 32 candidates, top-9 by (iou desc, K-position asc) ----
  if (lane < KK) {
    float iou = iou_ref(gt, pb[pi]);
    // ~bits(iou) strictly decreasing in iou (iou >= 0): smaller key ==
    // higher iou; ties -> lower K-position.
    u32 myk = ~__float_as_uint(iou);
    ik[lane] = myk;
    int r9 = 0;
#pragma unroll
    for (int i2 = 0; i2 < KK; ++i2) {
      u32 ki = ik[i2];
      r9 += ((ki < myk) || (ki == myk && i2 < lane)) ? 1 : 0;
    }
    if (r9 < NN) {
      int base = (b * GG + g) * NN + r9;
      out[base] = pi;               // pred_idx
      out[BB * GG * NN + base] = g; // gt_idx
    }
  }
}

extern "C" void kernel_launch(void* const* d_in, const int* in_sizes, int n_in,
                              void* d_out, int out_size, void* d_ws, size_t ws_size,
                              hipStream_t stream) {
  (void)in_sizes;
  (void)n_in;
  (void)out_size;
  (void)ws_size;
  const float4* pred = (const float4*)d_in[0];  // [B, Q, 4] f32
  const float4* gt = (const float4*)d_in[1];    // [B, G, 4] f32
  int* out = (int*)d_out;                       // [2 * B * G * N] int32
  u16* ws = (u16*)d_ws;                         // 16 MB bf16 range-mins
  atss_phase1<<<512, TH, 0, stream>>>(pred, gt, ws);
  atss_phase2<<<4096, 64, 0, stream>>>(pred, gt, ws, out);
}

// Round 7
// 86.932 us; speedup vs baseline: 53.3192x; 53.3192x over previous
//
#include <hip/hip_runtime.h>

#define BB 32
#define QQ 16384
#define GG 128
#define KK 32
#define NN 9
#define TT 16       // GTs per K1 block
#define TH 1024     // K1 block size
#define HR 8        // elements per K1 thread (half-Q split)
#define NRANGE 2048 // ranges per (b, GT); range r covers {r + j*NRANGE, j<8}
#define RPL 32      // ranges per K2 lane (contiguous)
#define CAP 192     // compacted candidate key capacity (3 rank slots)
#define ACAP 96     // per-GT active-range capacity (expected ~45)
#define LCAP 12     // per-lane candidate slots; lc <= ceil(ACAP*8/64) = 12
#define UF 4        // K1 load prefetch batch

typedef unsigned long long u64;
typedef unsigned int u32;
typedef unsigned short u16;

#define INFF __uint_as_float(0x7F800000u)

// packed ascending key: (float bits of nonneg key) << 32 | idx
// lexicographic u64 compare == (value asc, index asc) == jax top_k tie rule
__device__ __forceinline__ u64 pack_asc(float key, u32 idx) {
  return (((u64)__float_as_uint(key)) << 32) | (u64)idx;
}

// EXACT reference squared distance: ((dx^2+dy^2)+dz^2)+dw^2, no contraction.
__device__ __forceinline__ float dist2_ref(const float4 g, const float4 p) {
#pragma clang fp contract(off)
  float dx = g.x - p.x;
  float dy = g.y - p.y;
  float dz = g.z - p.z;
  float dw = g.w - p.w;
  float s = dx * dx + dy * dy;
  s = s + dz * dz;
  s = s + dw * dw;
  return s;
}

// IoU exactly as reference (cxcywh -> xyxy, clip, same op order)
__device__ __forceinline__ float iou_ref(const float4 g, const float4 p) {
#pragma clang fp contract(off)
  float gx1 = g.x - 0.5f * g.z, gy1 = g.y - 0.5f * g.w;
  float gx2 = g.x + 0.5f * g.z, gy2 = g.y + 0.5f * g.w;
  float px1 = p.x - 0.5f * p.z, py1 = p.y - 0.5f * p.w;
  float px2 = p.x + 0.5f * p.z, py2 = p.y + 0.5f * p.w;
  float ltx = fmaxf(gx1, px1), lty = fmaxf(gy1, py1);
  float rbx = fminf(gx2, px2), rby = fminf(gy2, py2);
  float wx = fmaxf(rbx - ltx, 0.0f), wy = fmaxf(rby - lty, 0.0f);
  float inter = wx * wy;
  float aa = (gx2 - gx1) * (gy2 - gy1);
  float ab = (px2 - px1) * (py2 - py1);
  return inter / ((aa + ab) - inter);
}

// monotone bijection float -> u32 (total order preserved; no NaN inputs)
__device__ __forceinline__ u32 f2ord(float f) {
  u32 b = __float_as_uint(f);
  return (b & 0x80000000u) ? ~b : (b | 0x80000000u);
}
__device__ __forceinline__ float ord2f(u32 k) {
  return __uint_as_float((k & 0x80000000u) ? (k & 0x7FFFFFFFu) : ~k);
}

// round-UP-in-value f32 -> bf16 (monotone, result >= input):
// positives: +0xFFFF then truncate; negatives: truncation moves toward 0.
__device__ __forceinline__ u16 bf16up(float x) {
  u32 b = __float_as_uint(x);
  if (!(b >> 31)) b += 0xFFFFu;
  return (u16)(b >> 16);
}

// ================= K1: per-range min of d2 (stored in d2-SPACE) ==========
// 512 blocks x 1024 thr; block = (batch b, GT-group m of 16, Q-half h).
// Thread t handles range r = h*1024 + t: elements {r + j*NRANGE, j<8}.
// Inner loop accumulates s = |p|^2 - 2 g.p (5 ops/pair); the per-GT
// constant |g|^2 is added ONCE after the min, so the stored value is
// min-d2 (fma form) -- bf16's 2^-7 relative error is then relative to
// d2 (~0.05 scale), not |g|^2 (~1 scale). R6's s-space bf16 storage made
// the threshold slack ~70% of d2_32 -> candidate blowup -> fallback storm.
__global__ __launch_bounds__(TH, 8) void atss_phase1(
    const float4* __restrict__ pred, const float4* __restrict__ gtb,
    u16* __restrict__ ws) {
  const int t = threadIdx.x;
  // XCD swizzle: f&7 = b>>2 -> same-batch blocks share an XCD.
  const int f = blockIdx.x;
  const int b = (f & 7) * 4 + (f >> 7);
  const int m = (f >> 3) & 7;
  const int h = (f >> 6) & 1;
  const int g0 = m * TT;

  float4 G[TT];
  float g2[TT];  // |g|^2, SAME fma form as the proven margin analysis
#pragma unroll
  for (int gg = 0; gg < TT; ++gg) {
    G[gg] = gtb[b * GG + g0 + gg];
    g2[gg] = fmaf(G[gg].x, G[gg].x,
             fmaf(G[gg].y, G[gg].y,
             fmaf(G[gg].z, G[gg].z, G[gg].w * G[gg].w)));
  }

  const float4* pb = pred + (size_t)b * QQ;
  const int r = h * 1024 + t;  // this thread's range id

  float mn[TT];
#pragma unroll
  for (int gg = 0; gg < TT; ++gg) mn[gg] = INFF;

  float4 P[UF];
#pragma unroll
  for (int u = 0; u < UF; ++u) P[u] = pb[r + u * NRANGE];
#pragma unroll
  for (int j = 0; j < HR; j += UF) {
    float4 C[UF];
#pragma unroll
    for (int u = 0; u < UF; ++u) C[u] = P[u];
    if (j + UF < HR) {
#pragma unroll
      for (int u = 0; u < UF; ++u) P[u] = pb[r + (j + UF + u) * NRANGE];
    }
#pragma unroll
    for (int u = 0; u < UF; ++u) {
      float4 p = C[u];
      float pp = fmaf(p.x, p.x, fmaf(p.y, p.y, fmaf(p.z, p.z, p.w * p.w)));
      float qx = p.x + p.x, qy = p.y + p.y, qz = p.z + p.z, qw = p.w + p.w;
#pragma unroll
      for (int gg = 0; gg < TT; ++gg) {
        float acc = fmaf(-G[gg].x, qx, pp);
        acc = fmaf(-G[gg].y, qy, acc);
        acc = fmaf(-G[gg].z, qz, acc);
        acc = fmaf(-G[gg].w, qw, acc);
        mn[gg] = fminf(mn[gg], acc);
      }
    }
  }
  // ws layout: [(b*8 + m)*16 + gg][NRANGE] bf16 of (min_s + |g|^2) = min_d2
  u16* seg = ws + (size_t)((b * 8 + m) * TT) * NRANGE;
#pragma unroll
  for (int gg = 0; gg < TT; ++gg)
    seg[gg * NRANGE + r] = bf16up(mn[gg] + g2[gg]);
}

// ================= K2: per-GT selection, one 64-lane wave =================
// 4096 blocks x 64 thr. No dependent ballot/SALU chains: one shfl_up scan
// per compaction, broadcast-LDS rank select (3 slots, n <= 192), 16-iter
// radix. All thresholds in d2-space with tight (proven-scale) margins.
__global__ __launch_bounds__(64, 4) void atss_phase2(
    const float4* __restrict__ pred, const float4* __restrict__ gtb,
    const u16* __restrict__ ws, int* __restrict__ out) {
  __shared__ u64 kl[LCAP][64];  // per-lane strided candidate buffers (6 KB)
  __shared__ u64 kc[CAP];       // compacted (d,idx) keys
  __shared__ u16 sact[ACAP];    // active range ids
  __shared__ u32 ik[KK];        // iou rank keys
  __shared__ int kidx[KK];      // K-position -> pred idx (rank scatter)

  const int lane = threadIdx.x;
  // XCD swizzle consistent with K1: f&7 = b>>2.
  const int f = blockIdx.x;
  const int x = f & 7;
  const int jd = f >> 3;
  const int b = x * 4 + (jd & 3);
  const int g = jd >> 2;

  const float4 gt = gtb[b * GG + g];  // wave-uniform
  const float4* pb = pred + (size_t)b * QQ;
  const u16* vsrc =
      ws + (size_t)((b * 8 + (g >> 4)) * TT + (g & 15)) * NRANGE;

  // ---- load this GT's 2048 bf16 range-min-d2; lane owns 32 contiguous --
  float V[RPL];
  {
    const uint4* v4 = (const uint4*)(vsrc + lane * RPL);
    uint4 qa = v4[0], qb = v4[1], qc = v4[2], qd = v4[3];
#define UNPK(W, base)                                   \
  V[(base)] = __uint_as_float((W) << 16);               \
  V[(base) + 1] = __uint_as_float((W) & 0xFFFF0000u);
    UNPK(qa.x, 0) UNPK(qa.y, 2) UNPK(qa.z, 4) UNPK(qa.w, 6)
    UNPK(qb.x, 8) UNPK(qb.y, 10) UNPK(qb.z, 12) UNPK(qb.w, 14)
    UNPK(qc.x, 16) UNPK(qc.y, 18) UNPK(qc.z, 20) UNPK(qc.w, 22)
    UNPK(qd.x, 24) UNPK(qd.y, 26) UNPK(qd.z, 28) UNPK(qd.w, 30)
#undef UNPK
  }

  // ---- per-lane 2 smallest of its 32 values (branchless) ----
  float m1 = INFF, m2 = INFF;
#pragma unroll
  for (int k = 0; k < RPL; ++k) {
    float v = V[k];
    float nm1 = fminf(m1, v);
    m2 = fminf(m2, fmaxf(m1, v));
    m1 = nm1;
  }

  // ---- U = 32nd smallest of the 128 kept stored-d2 (2 per lane) ----
  // 16-round ballot radix on ordered keys. Stored values are bf16-grid
  // floats (low 16 mantissa bits zero) -> pref|0xFFFF recovers the EXACT
  // 32nd smallest stored value (no radix slack). Bound: >= 32 DISTINCT
  // ranges have stored-min <= U; round-up storage -> their fma-min <= U.
  u32 k1 = f2ord(m1), k2 = f2ord(m2);
  u32 pref = 0;
#pragma unroll
  for (int bit = 31; bit >= 16; --bit) {
    u32 tr = pref | (1u << bit);
    int c = __popcll(__ballot(k1 < tr)) + __popcll(__ballot(k2 < tr));
    if (c < 32) pref = tr;
  }
  const float Us = ord2f(pref | 0xFFFFu);  // wave-uniform

  // T: witnesses' ref-d2 <= fma-min + (2e-5 rel + 4e-6 abs) [proven
  // R5-R8 fma-vs-ref margin] <= U + d(U). sUs additionally covers the
  // bf16 round-UP of a kept range's min (<= 2^-7 rel) + f32 add rounding.
  const float T = fmaxf(Us, 0.0f) * 1.0001f + 1e-5f;   // d2-space test
  const float sUs = T * 1.009f + 1e-5f;                // stored-space test

  // ---- compact active ranges: ONE prefix scan, zero ballots ----
  u32 amask = 0;
#pragma unroll
  for (int k = 0; k < RPL; ++k) amask |= (V[k] <= sUs) ? (1u << k) : 0u;
  int cnt = __popc(amask);
  int pre = cnt;
#pragma unroll
  for (int sj = 1; sj < 64; sj <<= 1) {
    int o = __shfl_up(pre, sj, 64);
    if (lane >= sj) pre += o;
  }
  const int na = __shfl(pre, 63, 64);  // wave-uniform total
  {
    int pos = pre - cnt;
    u32 mrem = amask;
    while (mrem) {
      int k = __ffs(mrem) - 1;
      mrem &= mrem - 1;
      if (pos < ACAP) sact[pos] = (u16)(lane * RPL + k);
      ++pos;
    }
  }

  // ---- exact-d2 collection into per-lane buffers (no cross-lane coord) --
  bool bad = (na > ACAP);
  int lc = 0;
  int n = 0;
  if (!bad) {
    // flat item space: item it = lane + 64*trip; entry it>>3 (8 lanes per
    // entry), element (it&7)*NRANGE. 2-deep pipeline hides sact+VMEM lat.
    const int total = na * HR;
    const int trips = (total + 63) >> 6;
    int it = lane;
    bool cv = it < total;
    int ci = 0;
    float4 cp;
    if (cv) {
      int e = sact[it >> 3];
      ci = (int)e + (it & 7) * NRANGE;
      cp = pb[ci];
    }
    for (int tr = 0; tr < trips; ++tr) {
      int itn = it + 64;
      bool nv = itn < total;
      int ni = 0;
      float4 np;
      if (nv) {
        int e = sact[itn >> 3];
        ni = (int)e + (itn & 7) * NRANGE;
        np = pb[ni];
      }
      if (cv) {
        float d2 = dist2_ref(gt, cp);
        if (d2 <= T) {
          // d = sqrtf(d2): IEEE, == jnp. lc <= trips <= LCAP structurally.
          if (lc < LCAP) kl[lc][lane] = pack_asc(sqrtf(d2), (u32)ci);
          ++lc;
        }
      }
      it = itn;
      cv = nv;
      ci = ni;
      cp = np;
    }

    // ---- compact candidate count: second prefix scan ----
    int pre2 = lc;
#pragma unroll
    for (int sj = 1; sj < 64; sj <<= 1) {
      int o = __shfl_up(pre2, sj, 64);
      if (lane >= sj) pre2 += o;
    }
    n = __shfl(pre2, 63, 64);  // wave-uniform; >= 32 by the bound
    int excl = pre2 - lc;
    for (int i = 0; i < lc; ++i) {
      int dst = excl + i;
      if (dst < CAP) kc[dst] = kl[i][lane];
    }
    bad = (n > CAP);
  }

  // ---- pathological-only exact serial fallback (should never fire) ----
  if (bad) {
    if (lane == 0) {
      u64 best[KK];
      for (int l = 0; l < KK; ++l) best[l] = ~0ull;
      for (int i = 0; i < QQ; ++i) {
        float d = sqrtf(dist2_ref(gt, pb[i]));
        u64 pk = pack_asc(d, (u32)i);
        if (pk < best[KK - 1]) {
          int pos = KK - 1;
          while (pos > 0 && best[pos - 1] > pk) {
            best[pos] = best[pos - 1];
            --pos;
          }
          best[pos] = pk;
        }
      }
      for (int l = 0; l < KK; ++l) kidx[l] = (int)(best[l] & 0xFFFFFFFFull);
    }
  } else {
    // ---- top-32 rank select over n <= 192 keys: broadcast LDS reads ----
    // (independent ds_read_b64s, 4-unrolled; no dependent shuffle chain).
    // Ranks unique (keys embed unique idx); ranks 0..31 all exist (n>=32).
    // Scatter idx to kidx[rank] via LDS (no ds_permute: its dest-lane addr
    // wraps mod 64 for ranks >= 64).
    u64 myA = (lane < n) ? kc[lane] : ~0ull;
    u64 myB = (lane + 64 < n) ? kc[lane + 64] : ~0ull;
    u64 myC = (lane + 128 < n) ? kc[lane + 128] : ~0ull;
    int rA = 0, rB = 0, rC = 0;
    const int nslots = (n > 128) ? 3 : ((n > 64) ? 2 : 1);  // uniform
    if (nslots == 1) {
      int i = 0;
      for (; i + 4 <= n; i += 4) {
        u64 a0 = kc[i], a1 = kc[i + 1], a2 = kc[i + 2], a3 = kc[i + 3];
        rA += (int)(a0 < myA) + (int)(a1 < myA) + (int)(a2 < myA) +
              (int)(a3 < myA);
      }
      for (; i < n; ++i) rA += (int)(kc[i] < myA);
    } else if (nslots == 2) {
      int i = 0;
      for (; i + 4 <= n; i += 4) {
        u64 a0 = kc[i], a1 = kc[i + 1], a2 = kc[i + 2], a3 = kc[i + 3];
        rA += (int)(a0 < myA) + (int)(a1 < myA) + (int)(a2 < myA) +
              (int)(a3 < myA);
        rB += (int)(a0 < myB) + (int)(a1 < myB) + (int)(a2 < myB) +
              (int)(a3 < myB);
      }
      for (; i < n; ++i) {
        u64 a0 = kc[i];
        rA += (int)(a0 < myA);
        rB += (int)(a0 < myB);
      }
    } else {
      int i = 0;
      for (; i + 4 <= n; i += 4) {
        u64 a0 = kc[i], a1 = kc[i + 1], a2 = kc[i + 2], a3 = kc[i + 3];
        rA += (int)(a0 < myA) + (int)(a1 < myA) + (int)(a2 < myA) +
              (int)(a3 < myA);
        rB += (int)(a0 < myB) + (int)(a1 < myB) + (int)(a2 < myB) +
              (int)(a3 < myB);
        rC += (int)(a0 < myC) + (int)(a1 < myC) + (int)(a2 < myC) +
              (int)(a3 < myC);
      }
      for (; i < n; ++i) {
        u64 a0 = kc[i];
        rA += (int)(a0 < myA);
        rB += (int)(a0 < myB);
        rC += (int)(a0 < myC);
      }
    }
    if (lane < n && rA < KK) kidx[rA] = (int)(myA & 0xFFFFFFFFull);
    if (nslots >= 2 && lane + 64 < n && rB < KK)
      kidx[rB] = (int)(myB & 0xFFFFFFFFull);
    if (nslots >= 3 && lane + 128 < n && rC < KK)
      kidx[rC] = (int)(myC & 0xFFFFFFFFull);
  }
  // same-wave DS ordering: kidx writes visible to this wave's reads
  const int pi = (lane < KK) ? kidx[lane] : 0;

  // ---- IoU of the 32 candidates, top-9 by (iou desc, K-position asc) ----
  if (lane < KK) {
    float iou = iou_ref(gt, pb[pi]);
    // ~bits(iou) strictly decreasing in iou (iou >= 0): smaller key ==
    // higher iou; ties -> lower K-position.
    u32 myk = ~__float_as_uint(iou);
    ik[lane] = myk;
    int r9 = 0;
#pragma unroll
    for (int i2 = 0; i2 < KK; ++i2) {
      u32 ki = ik[i2];
      r9 += ((ki < myk) || (ki == myk && i2 < lane)) ? 1 : 0;
    }
    if (r9 < NN) {
      int base = (b * GG + g) * NN + r9;
      out[base] = pi;               // pred_idx
      out[BB * GG * NN + base] = g; // gt_idx
    }
  }
}

extern "C" void kernel_launch(void* const* d_in, const int* in_sizes, int n_in,
                              void* d_out, int out_size, void* d_ws, size_t ws_size,
                              hipStream_t stream) {
  (void)in_sizes;
  (void)n_in;
  (void)out_size;
  (void)ws_size;
  const float4* pred = (const float4*)d_in[0];  // [B, Q, 4] f32
  const float4* gt = (const float4*)d_in[1];    // [B, G, 4] f32
  int* out = (int*)d_out;                       // [2 * B * G * N] int32
  u16* ws = (u16*)d_ws;                         // 16 MB bf16 range-min d2
  atss_phase1<<<512, TH, 0, stream>>>(pred, gt, ws);
  atss_phase2<<<4096, 64, 0, stream>>>(pred, gt, ws, out);
}